// Round 6
// baseline (393.012 us; speedup 1.0000x reference)
//
#include <hip/hip_runtime.h>
#include <math.h>

// TranAD fused forward, 2 blocks per batch element (grid=256, 1024 thr).
// Round-6 restructure: ALL weights pre-transposed to [k][m] in workspace by
// k_prep; GEMMs read weights from GLOBAL (L1-resident, VMEM pipe) and x from
// LDS (broadcast float4) -- round-5 counters showed the kernel was LDS-issue
// bound (~460K cyc/CU of ds_read for weights). No more LDS weight staging.
// K/V exchanged pairwise via sc0 sc1 (IF$-coherent, no L2 wb/inv) with the
// Q-projection overlapping the exchange. Co-residency: 104KB LDS > 80KB =>
// 1 block/CU => all 256 blocks resident => pairwise spin cannot deadlock.
// Flags start 0 each iteration (harness memsets workspace).

#define TPB 1024
#define RH 50
#define SQ32 5.656854249492381f

#ifndef __has_builtin
#define __has_builtin(x) 0
#endif
#if __has_builtin(__builtin_amdgcn_exp2f)
#define EXP2(x) __builtin_amdgcn_exp2f(x)
#else
#define EXP2(x) exp2f(x)
#endif

typedef float v2f __attribute__((ext_vector_type(2)));
typedef float v4f __attribute__((ext_vector_type(4)));

struct KParams { const void* p[36]; };

// Transposed-weight workspace offsets (floats)
// qkv (5x [64][192]): 0,12288,...  out (5x [64][64]): 61440+4096i
// l1 (3x [64][16]): 81920+1024i    l2 (3x [16][64]): 84992+1024i
// fcn ([64][32]): 88064            total 90112 floats
#define WT_QKV(i) (12288 * (i))
#define WT_OUT(i) (61440 + 4096 * (i))
#define WT_L1(i)  (81920 + 1024 * (i))
#define WT_L2(i)  (84992 + 1024 * (i))
#define WT_FCN    88064

// ---------------------------------------------------------------------------
// prep: transpose weights into [k][M] layout. One block per matrix.
// ---------------------------------------------------------------------------
static __device__ const int g_tbl[17][4] = {
    {2, 192, 6, 0},     {6, 192, 6, 12288}, {10, 192, 6, 24576},
    {14, 192, 6, 36864},{18, 192, 6, 49152},
    {4, 64, 6, 61440},  {8, 64, 6, 65536},  {12, 64, 6, 69632},
    {16, 64, 6, 73728}, {20, 64, 6, 77824},
    {22, 16, 6, 81920}, {26, 16, 6, 82944}, {30, 16, 6, 83968},
    {24, 64, 4, 84992}, {28, 64, 4, 86016}, {32, 64, 4, 87040},
    {34, 32, 6, 88064}};

__global__ __launch_bounds__(256) void k_prep(KParams prm, float* __restrict__ wt)
{
    const int e = blockIdx.x;
    const float* src = (const float*)prm.p[g_tbl[e][0]];
    const int M = g_tbl[e][1], ks = g_tbl[e][2], dst = g_tbl[e][3];
    const int N = M << ks, km = (1 << ks) - 1;
    for (int i = threadIdx.x; i < N; i += 256) {
        int m = i >> ks, k = i & km;
        wt[dst + k * M + m] = src[i];
    }
}

// ---------------------------------------------------------------------------
// GEMM helpers: x from LDS, weights from GLOBAL [k][M] (pitch WP)
// ---------------------------------------------------------------------------
// 2 rows x 4 cols, v2f accumulators (invites v_pk_fma_f32)
template<int K, int WP>
__device__ __forceinline__ void gemm24(const float* __restrict__ x0,
                                       const float* __restrict__ x1,
                                       const float* __restrict__ gw, v2f acc[4])
{
#pragma unroll 4
    for (int kk = 0; kk < K / 4; ++kk) {
        v4f xa = *reinterpret_cast<const v4f*>(x0 + 4 * kk);
        v4f xb = *reinterpret_cast<const v4f*>(x1 + 4 * kk);
#pragma unroll
        for (int j = 0; j < 4; ++j) {
            v4f w = *reinterpret_cast<const v4f*>(gw + (size_t)(4 * kk + j) * WP);
            v2f xj = {xa[j], xb[j]};
#pragma unroll
            for (int c = 0; c < 4; ++c) {
                v2f wc = {w[c], w[c]};
                acc[c] = __builtin_elementwise_fma(xj, wc, acc[c]);
            }
        }
    }
}

// 1 row x 4 cols
template<int K, int WP>
__device__ __forceinline__ void gemm14(const float* __restrict__ x,
                                       const float* __restrict__ gw, float acc[4])
{
#pragma unroll 4
    for (int kk = 0; kk < K / 4; ++kk) {
        v4f xv = *reinterpret_cast<const v4f*>(x + 4 * kk);
#pragma unroll
        for (int j = 0; j < 4; ++j) {
            v4f w = *reinterpret_cast<const v4f*>(gw + (size_t)(4 * kk + j) * WP);
#pragma unroll
            for (int c = 0; c < 4; ++c) acc[c] = fmaf(xv[j], w[c], acc[c]);
        }
    }
}

// ---------------------------------------------------------------------------
// K and V projections (chunks 1,2 of qkv), own 50 rows -> LDS + global(sc0sc1)
// ---------------------------------------------------------------------------
__device__ __forceinline__ void kv_stage(const float* __restrict__ Xkv,
    const float* __restrict__ gw /* qkv base, pitch 192 */,
    const float* __restrict__ Bi, int b, int base,
    float2* __restrict__ Ks, float2* __restrict__ Vs,
    float2* __restrict__ Kg, float2* __restrict__ Vg, int tid)
{
    if (tid >= 800) return;
    const int c = (tid >= 400) ? 2 : 1;
    const int u = tid - ((c == 2) ? 400 : 0);
    const int r0 = u >> 4, cg = u & 15;
    v2f acc[4] = {};
    gemm24<64, 192>(Xkv + r0 * 68, Xkv + (r0 + 25) * 68, gw + c * 64 + 4 * cg, acc);
    v4f bb = *reinterpret_cast<const v4f*>(Bi + c * 64 + 4 * cg);
    float2* Ls = (c == 1) ? Ks : Vs;
    float2* Lg = (c == 1) ? Kg : Vg;
    const int h0 = 2 * cg;
#pragma unroll
    for (int rr = 0; rr < 2; ++rr) {
        int sg = base + r0 + 25 * rr;
        float2 p0 = make_float2(acc[0][rr] + bb[0], acc[1][rr] + bb[1]);
        float2 p1 = make_float2(acc[2][rr] + bb[2], acc[3][rr] + bb[3]);
        Ls[h0 * 102 + sg] = p0;
        Ls[(h0 + 1) * 102 + sg] = p1;
        v4f gv = {p0.x, p0.y, p1.x, p1.y};
        float2* gp = Lg + ((size_t)b * 100 + sg) * 32 + h0;
        asm volatile("global_store_dwordx4 %0, %1, off sc0 sc1" :: "v"(gp), "v"(gv) : "memory");
    }
}

// drain own sc0sc1 stores, then raise flag
__device__ __forceinline__ void flag_pub(int* flagme, int st, int tid)
{
    asm volatile("s_waitcnt vmcnt(0)" ::: "memory");
    __syncthreads();
    if (tid == 0)
        asm volatile("global_store_dword %0, %1, off sc0 sc1" :: "v"(flagme), "v"(st) : "memory");
}

// q projection (chunk 0) -> R1; overlaps the partner's exchange
__device__ __forceinline__ void q_stage(const float* __restrict__ Xq,
    const float* __restrict__ gw, const float* __restrict__ Bi,
    float* __restrict__ Q, int tid)
{
    if (tid >= 400) return;
    const int r0 = tid >> 4, cg = tid & 15;
    v2f acc[4] = {};
    gemm24<64, 192>(Xq + r0 * 68, Xq + (r0 + 25) * 68, gw + 4 * cg, acc);
    v4f bb = *reinterpret_cast<const v4f*>(Bi + 4 * cg);
#pragma unroll
    for (int rr = 0; rr < 2; ++rr) {
        v4f o = {acc[0][rr] + bb[0], acc[1][rr] + bb[1],
                 acc[2][rr] + bb[2], acc[3][rr] + bb[3]};
        *reinterpret_cast<v4f*>(Q + (r0 + 25 * rr) * 68 + 4 * cg) = o;
    }
}

// spin (relaxed sc0sc1, no cache maintenance) then pull partner K/V into LDS
__device__ __forceinline__ void kv_wait(const int* flagpt, int st,
    const float2* __restrict__ Kg, const float2* __restrict__ Vg,
    int b, int pbase, float2* __restrict__ Ks, float2* __restrict__ Vs, int tid)
{
    if (tid == 0) {
        int f;
        for (;;) {
            asm volatile("global_load_dword %0, %1, off sc0 sc1\n\ts_waitcnt vmcnt(0)"
                         : "=v"(f) : "v"(flagpt) : "memory");
            if (f >= st) break;
            __builtin_amdgcn_s_sleep(8);
        }
    }
    __syncthreads();
    for (int i = tid; i < 1600; i += TPB) {
        const int isV = i >= 800;
        const int j = i - (isV ? 800 : 0);
        const int sl = j >> 4, hp = j & 15;
        const int sg = pbase + sl;
        const float2* gp = (isV ? Vg : Kg) + ((size_t)b * 100 + sg) * 32 + 2 * hp;
        v4f v;
        asm volatile("global_load_dwordx4 %0, %1, off sc0 sc1\n\ts_waitcnt vmcnt(0)"
                     : "=v"(v) : "v"(gp) : "memory");
        float2* Ls = isV ? Vs : Ks;
        Ls[(2 * hp) * 102 + sg] = make_float2(v[0], v[1]);
        Ls[(2 * hp + 1) * 102 + sg] = make_float2(v[2], v[3]);
    }
    __syncthreads();
}

// ---------------------------------------------------------------------------
// attention: own 50 q-rows, full 100-key K/V. task = (head, 7-query group).
// K read as float4 pairs (2 keys/read); 256 threads, conflict-free banks.
// ---------------------------------------------------------------------------
__device__ __forceinline__ void attn_block(float* __restrict__ Q,
    const float2* __restrict__ Ks, const float2* __restrict__ Vs, int tid)
{
    if (tid < 256) {
        const int h = tid >> 3, g = tid & 7;
        const int lq0 = 7 * g;
        const int nq = (lq0 + 7 <= RH) ? 7 : (RH - lq0);
        const v4f* K4 = reinterpret_cast<const v4f*>(Ks + h * 102);
        const v4f* V4 = reinterpret_cast<const v4f*>(Vs + h * 102);
        const float SCALE = 0.7071067811865476f * 1.4426950408889634f;  // /sqrt(2)*log2e
        float q0[7], q1[7], mx[7], sum[7], a0[7], a1[7];
#pragma unroll
        for (int j = 0; j < 7; ++j) {
            float2 qv = (j < nq) ? *reinterpret_cast<const float2*>(Q + (lq0 + j) * 68 + 2 * h)
                                 : make_float2(0.f, 0.f);
            q0[j] = qv.x * SCALE; q1[j] = qv.y * SCALE;
            mx[j] = -1e30f; sum[j] = 0.f; a0[j] = 0.f; a1[j] = 0.f;
        }
        for (int s2 = 0; s2 < 50; ++s2) {
            v4f kp = K4[s2];
#pragma unroll
            for (int j = 0; j < 7; ++j) {
                mx[j] = fmaxf(mx[j], fmaf(q0[j], kp[0], q1[j] * kp[1]));
                mx[j] = fmaxf(mx[j], fmaf(q0[j], kp[2], q1[j] * kp[3]));
            }
        }
        for (int s2 = 0; s2 < 50; ++s2) {
            v4f kp = K4[s2];
            v4f vp = V4[s2];
#pragma unroll
            for (int j = 0; j < 7; ++j) {
                float e0 = EXP2(fmaf(q0[j], kp[0], fmaf(q1[j], kp[1], -mx[j])));
                float e1 = EXP2(fmaf(q0[j], kp[2], fmaf(q1[j], kp[3], -mx[j])));
                sum[j] += e0 + e1;
                a0[j] = fmaf(e0, vp[0], fmaf(e1, vp[2], a0[j]));
                a1[j] = fmaf(e0, vp[1], fmaf(e1, vp[3], a1[j]));
            }
        }
#pragma unroll
        for (int j = 0; j < 7; ++j)
            if (j < nq) {
                float inv = 1.f / sum[j];
                *reinterpret_cast<float2*>(Q + (lq0 + j) * 68 + 2 * h) =
                    make_float2(a0[j] * inv, a1[j] * inv);
            }
    }
}

// out-projection + residual in place (weights global [k][64])
__device__ __forceinline__ void out_res(const float* __restrict__ Ain,
    const float* __restrict__ gw, const float* __restrict__ Bi,
    float* __restrict__ Sres, int tid)
{
    if (tid >= 400) return;
    const int r0 = tid >> 4, cg = tid & 15;
    v2f acc[4] = {};
    gemm24<64, 64>(Ain + r0 * 68, Ain + (r0 + 25) * 68, gw + 4 * cg, acc);
    v4f bb = *reinterpret_cast<const v4f*>(Bi + 4 * cg);
#pragma unroll
    for (int rr = 0; rr < 2; ++rr) {
        float* sp = Sres + (r0 + 25 * rr) * 68 + 4 * cg;
        v4f s0 = *reinterpret_cast<v4f*>(sp);
        *reinterpret_cast<v4f*>(sp) =
            (v4f){acc[0][rr] + bb[0] + s0[0], acc[1][rr] + bb[1] + s0[1],
                  acc[2][rr] + bb[2] + s0[2], acc[3][rr] + bb[3] + s0[3]};
    }
}

// X += W2 @ (W1 @ X + b1) + b2  (LeakyReLU(True) == identity)
__device__ __forceinline__ void ffn_block(float* __restrict__ X,
    const float* __restrict__ w1, const float* __restrict__ B1,
    const float* __restrict__ w2, const float* __restrict__ B2,
    float* __restrict__ Hs, int tid)
{
    __syncthreads();                       // X final
    if (tid < 200) {
        const int r = tid >> 2, c4 = tid & 3;
        float a[4] = {0, 0, 0, 0};
        gemm14<64, 16>(X + r * 68, w1 + 4 * c4, a);
        v4f bb = *reinterpret_cast<const v4f*>(B1 + 4 * c4);
        *reinterpret_cast<v4f*>(Hs + r * 20 + 4 * c4) =
            (v4f){a[0] + bb[0], a[1] + bb[1], a[2] + bb[2], a[3] + bb[3]};
    }
    __syncthreads();
    if (tid < 400) {
        const int r0 = tid >> 4, cg = tid & 15;
        v2f acc[4] = {};
        gemm24<16, 64>(Hs + r0 * 20, Hs + (r0 + 25) * 20, w2 + 4 * cg, acc);
        v4f bb = *reinterpret_cast<const v4f*>(B2 + 4 * cg);
#pragma unroll
        for (int rr = 0; rr < 2; ++rr) {
            float* xp = X + (r0 + 25 * rr) * 68 + 4 * cg;
            v4f u = *reinterpret_cast<v4f*>(xp);
            *reinterpret_cast<v4f*>(xp) =
                (v4f){acc[0][rr] + bb[0] + u[0], acc[1][rr] + bb[1] + u[1],
                      acc[2][rr] + bb[2] + u[2], acc[3][rr] + bb[3] + u[3]};
        }
    }
    __syncthreads();
}

// ---------------------------------------------------------------------------
__global__ __launch_bounds__(TPB) void k_fused(KParams prm, float* __restrict__ outp,
    const float* __restrict__ WT,
    float2* __restrict__ kx0, float2* __restrict__ vx0,
    float2* __restrict__ kx1, float2* __restrict__ vx1,
    int* __restrict__ flags)
{
    __shared__ float R0[RH * 68];        // s / mem
    __shared__ float R1[RH * 68];        // q / attn-out
    __shared__ float R3[RH * 68];        // t
    __shared__ float2 Ks[32 * 102];      // K: [head][seq], f4-pair readable
    __shared__ float2 Vs[32 * 102];
    __shared__ float Hs[RH * 20];
    __shared__ float X1s[RH * 36];

    const int tid = threadIdx.x;
    const int b = blockIdx.x & 127;
    const int half = blockIdx.x >> 7;
    const int base = half * RH;
    const int pbase = RH - base;
    int* flagme = flags + (b * 2 + half) * 32;
    int* flagpt = flags + (b * 2 + 1 - half) * 32;

    const float* src = (const float*)prm.p[0];
    const float* tgt = (const float*)prm.p[1];

#define ATT_STAGE(Xq, Xkv, WQKV, BQ, st)                                   \
    {                                                                      \
        float2* Kg = ((st) & 1) ? kx1 : kx0;                               \
        float2* Vg = ((st) & 1) ? vx1 : vx0;                               \
        kv_stage(Xkv, WQKV, BQ, b, base, Ks, Vs, Kg, Vg, tid);             \
        flag_pub(flagme, st, tid);                                         \
        q_stage(Xq, WQKV, BQ, R1, tid);                                    \
        kv_wait(flagpt, st, Kg, Vg, b, pbase, Ks, Vs, tid);                \
        attn_block(R1, Ks, Vs, tid);                                       \
        __syncthreads();                                                   \
    }

    for (int pass = 0; pass < 2; ++pass) {
        const float* Wq_enc = WT + WT_QKV(0);
        const float* Wq_sa  = WT + WT_QKV(pass ? 3 : 1);
        const float* Wq_ca  = WT + WT_QKV(pass ? 4 : 2);
        const float* Wo_enc = WT + WT_OUT(0);
        const float* Wo_sa  = WT + WT_OUT(pass ? 3 : 1);
        const float* Wo_ca  = WT + WT_OUT(pass ? 4 : 2);
        const float* W1_enc = WT + WT_L1(0);
        const float* W2_enc = WT + WT_L2(0);
        const float* W1_dec = WT + WT_L1(pass ? 2 : 1);
        const float* W2_dec = WT + WT_L2(pass ? 2 : 1);
        const float* Wf     = WT + WT_FCN;
        const float* Beq  = (const float*)prm.p[3];
        const float* Beo  = (const float*)prm.p[5];
        const float* Bel1 = (const float*)prm.p[23];
        const float* Bel2 = (const float*)prm.p[25];
        const float* Bsa  = (const float*)prm.p[pass ? 15 : 7];
        const float* Bsao = (const float*)prm.p[pass ? 17 : 9];
        const float* Bca  = (const float*)prm.p[pass ? 19 : 11];
        const float* Bcao = (const float*)prm.p[pass ? 21 : 13];
        const float* Bdl1 = (const float*)prm.p[pass ? 31 : 27];
        const float* Bdl2 = (const float*)prm.p[pass ? 33 : 29];
        const float* Bf   = (const float*)prm.p[35];
        float* outx = outp + (pass ? 409600 : 0);

        // ---- build s -> R0, tile tgt -> R3 ----
        __syncthreads();        // X1s (pass0 head) read; R0/R3 reuse
        for (int i = tid; i < RH * 64; i += TPB) {
            int l = i >> 6, d = i & 63;
            int lg = base + l;
            float sv = src[((size_t)lg * 128 + b) * 32 + (d & 31)];
            float v;
            if (d < 32) v = sv;
            else if (pass == 0) v = 0.f;
            else { float df = X1s[l * 36 + (d - 32)] - sv; v = df * df; }
            float div = __expf((float)d * -0.14391156831212787f);
            float pe = 1.4142135623730951f * __sinf((float)lg * div + 0.7853981633974483f);
            R0[l * 68 + d] = v * SQ32 + pe;
        }
        for (int i = tid; i < RH * 8; i += TPB) {
            int l = i >> 3, q4 = i & 7;
            int lg = base + l;
            float4 tv = *reinterpret_cast<const float4*>(tgt + ((size_t)lg * 128 + b) * 32 + 4 * q4);
            *reinterpret_cast<float4*>(R3 + l * 68 + 4 * q4) = tv;
            *reinterpret_cast<float4*>(R3 + l * 68 + 32 + 4 * q4) = tv;
        }
        __syncthreads();

        // ---- encoder self-attention + FFN (R0 becomes mem) ----
        ATT_STAGE(R0, R0, Wq_enc, Beq, pass * 3 + 1)
        out_res(R1, Wo_enc, Beo, R0, tid);
        ffn_block(R0, W1_enc, Bel1, W2_enc, Bel2, Hs, tid);   // leading+trailing barriers

        // ---- decoder self-attention ----
        ATT_STAGE(R3, R3, Wq_sa, Bsa, pass * 3 + 2)
        out_res(R1, Wo_sa, Bsao, R3, tid);
        __syncthreads();

        // ---- decoder cross-attention (q from t, kv from mem) ----
        ATT_STAGE(R3, R0, Wq_ca, Bca, pass * 3 + 3)
        out_res(R1, Wo_ca, Bcao, R3, tid);
        ffn_block(R3, W1_dec, Bdl1, W2_dec, Bdl2, Hs, tid);

        // ---- head: sigmoid(R3 @ Wf^T + bf) -> out (+ X1s for pass1's c) ----
        if (tid < 400) {
            const int r = tid >> 3, lp = tid & 7;
            float a[4] = {0, 0, 0, 0};
            gemm14<64, 32>(R3 + r * 68, Wf + 4 * lp, a);
            v4f bb = *reinterpret_cast<const v4f*>(Bf + 4 * lp);
            v4f o;
#pragma unroll
            for (int c = 0; c < 4; ++c) o[c] = 1.f / (1.f + __expf(-(a[c] + bb[c])));
            int rg = base + r;
            *reinterpret_cast<v4f*>(outx + ((size_t)rg * 128 + b) * 32 + 4 * lp) = o;
            if (pass == 0)
                *reinterpret_cast<v4f*>(X1s + r * 36 + 4 * lp) = o;
        }
    }
#undef ATT_STAGE
}

// ---------------------------------------------------------------------------
extern "C" void kernel_launch(void* const* d_in, const int* in_sizes, int n_in,
                              void* d_out, int out_size, void* d_ws, size_t ws_size,
                              hipStream_t stream)
{
    KParams prm;
    for (int i = 0; i < 36; ++i) prm.p[i] = d_in[i];
    float* WT = (float*)d_ws;                       // 90112 floats (pad to 98304)
    float2* kx0 = (float2*)(WT + 98304);            // 409600 float2 each
    float2* vx0 = kx0 + 409600;
    float2* kx1 = vx0 + 409600;
    float2* vx1 = kx1 + 409600;
    int* flags = (int*)(vx1 + 409600);              // 256 flags, 128B apart
    k_prep<<<dim3(17), dim3(256), 0, stream>>>(prm, WT);
    k_fused<<<dim3(256), dim3(TPB), 0, stream>>>(prm, (float*)d_out, WT,
                                                 kx0, vx0, kx1, vx1, flags);
}

// Round 7
// 188.345 us; speedup vs baseline: 2.0867x; 2.0867x over previous
//
#include <hip/hip_runtime.h>
#include <math.h>

// TranAD fused forward, 2 blocks per batch element (grid=256, 1024 thr).
// Round-7: revert to round-5 structure (LDS-staged weights; global weights
// regressed 2.1x -- VMEM-latency-bound). Attack the LDS-issue bound instead:
//   - x rows read as v4f (16 ds_read_b128 vs 64 ds_read_b32)
//   - 2 rows/thread: each weight b128 amortized over 2 rows
//   - K+V weight chunks staged side-by-side (RW pitch 132): one 800-thread
//     KV phase, exchange stores fused into the GEMM epilogue
// K/V exchanged pairwise via sc0 sc1 (IF$-coherent, no L2 wb/inv) with the
// Q-projection overlapping the exchange. Co-residency: 137.5KB LDS > 80KB =>
// 1 block/CU => all 256 blocks resident => pairwise spin cannot deadlock.
// Flags start 0 each iteration (harness memsets workspace).

#define TPB 1024
#define RH 50
#define SQ32 5.656854249492381f

#ifndef __has_builtin
#define __has_builtin(x) 0
#endif
#if __has_builtin(__builtin_amdgcn_exp2f)
#define EXP2(x) __builtin_amdgcn_exp2f(x)
#else
#define EXP2(x) exp2f(x)
#endif

typedef float v2f __attribute__((ext_vector_type(2)));
typedef float v4f __attribute__((ext_vector_type(4)));

struct KParams { const void* p[36]; };

// ---- stage W[MC][K] (row-major) transposed into Ws[k*WP + moff + m] ----
template<int K, int MC, int WP>
__device__ __forceinline__ void ldwp(const float* __restrict__ Wt, float* __restrict__ Ws,
                                     int moff, int tid)
{
    for (int i = tid; i < MC * K; i += TPB) {
        int m = i / K, k = i - m * K;       // K is 2^n -> shifts
        Ws[k * WP + moff + m] = Wt[i];
    }
}

// ---- 2 rows x 4 cols, x as v4f, weights LDS [k][*] pitch WP ----
template<int K, int WP>
__device__ __forceinline__ void gemm_dual24(const float* __restrict__ x0,
                                            const float* __restrict__ x1,
                                            const float* __restrict__ w, v2f acc[4])
{
#pragma unroll 4
    for (int kk = 0; kk < K / 4; ++kk) {
        v4f xa = *reinterpret_cast<const v4f*>(x0 + 4 * kk);
        v4f xb = *reinterpret_cast<const v4f*>(x1 + 4 * kk);
#pragma unroll
        for (int j = 0; j < 4; ++j) {
            v4f wv = *reinterpret_cast<const v4f*>(w + (size_t)(4 * kk + j) * WP);
            v2f xj = {xa[j], xb[j]};
#pragma unroll
            for (int c = 0; c < 4; ++c) {
                v2f wc = {wv[c], wv[c]};
                acc[c] = __builtin_elementwise_fma(xj, wc, acc[c]);
            }
        }
    }
}

// ---- 1 row x 4 cols, x as v4f ----
template<int K, int WP>
__device__ __forceinline__ void gemm14v(const float* __restrict__ x,
                                        const float* __restrict__ w, float acc[4])
{
#pragma unroll 4
    for (int kk = 0; kk < K / 4; ++kk) {
        v4f xv = *reinterpret_cast<const v4f*>(x + 4 * kk);
#pragma unroll
        for (int j = 0; j < 4; ++j) {
            v4f wv = *reinterpret_cast<const v4f*>(w + (size_t)(4 * kk + j) * WP);
#pragma unroll
            for (int c = 0; c < 4; ++c) acc[c] = fmaf(xv[j], wv[c], acc[c]);
        }
    }
}

// ---------------------------------------------------------------------------
// KV projection: 800 thr (tid<400: K chunk, 400..799: V chunk), 2 rows each.
// Writes interleaved KVs[h][101] (k->xy, v->zw) + direct sc0sc1 exchange store.
// ---------------------------------------------------------------------------
__device__ __forceinline__ void kv_gemm(const float* __restrict__ Xkv,
    const float* __restrict__ RW, const float* __restrict__ Bqkv,
    int b, int base, float4* __restrict__ KVs, float4* __restrict__ Gx, int tid)
{
    if (tid >= 800) return;
    const int isV = tid >= 400;
    const int u = tid - (isV ? 400 : 0);
    const int r0 = u >> 4, cg = u & 15;
    v2f acc[4] = {};
    gemm_dual24<64, 132>(Xkv + r0 * 68, Xkv + (r0 + 25) * 68,
                         RW + (isV ? 64 : 0) + 4 * cg, acc);
    v4f bb = *reinterpret_cast<const v4f*>(Bqkv + (isV ? 128 : 64) + 4 * cg);
    const int h0 = 2 * cg;
    const int off = isV ? 2 : 0;
#pragma unroll
    for (int rr = 0; rr < 2; ++rr) {
        int sg = base + r0 + 25 * rr;
        v2f p0 = {acc[0][rr] + bb[0], acc[1][rr] + bb[1]};
        v2f p1 = {acc[2][rr] + bb[2], acc[3][rr] + bb[3]};
        *reinterpret_cast<v2f*>(reinterpret_cast<float*>(KVs + h0 * 101 + sg) + off) = p0;
        *reinterpret_cast<v2f*>(reinterpret_cast<float*>(KVs + (h0 + 1) * 101 + sg) + off) = p1;
        float* g0 = reinterpret_cast<float*>(Gx + ((size_t)b * 100 + sg) * 32 + h0) + off;
        float* g1 = reinterpret_cast<float*>(Gx + ((size_t)b * 100 + sg) * 32 + h0 + 1) + off;
        asm volatile("global_store_dwordx2 %0, %1, off sc0 sc1" :: "v"(g0), "v"(p0) : "memory");
        asm volatile("global_store_dwordx2 %0, %1, off sc0 sc1" :: "v"(g1), "v"(p1) : "memory");
    }
}

// drain own sc0sc1 stores, barrier, raise flag
__device__ __forceinline__ void flag_pub(int* flagme, int st, int tid)
{
    asm volatile("s_waitcnt vmcnt(0)" ::: "memory");
    __syncthreads();
    if (tid == 0)
        asm volatile("global_store_dword %0, %1, off sc0 sc1" :: "v"(flagme), "v"(st) : "memory");
}

// q projection (chunk 0 of staged RW), 400 thr, 2 rows each -> R1
__device__ __forceinline__ void q_gemm(const float* __restrict__ Xq,
    const float* __restrict__ RW, const float* __restrict__ Bqkv,
    float* __restrict__ Q, int tid)
{
    if (tid >= 400) return;
    const int r0 = tid >> 4, cg = tid & 15;
    v2f acc[4] = {};
    gemm_dual24<64, 132>(Xq + r0 * 68, Xq + (r0 + 25) * 68, RW + 4 * cg, acc);
    v4f bb = *reinterpret_cast<const v4f*>(Bqkv + 4 * cg);
#pragma unroll
    for (int rr = 0; rr < 2; ++rr)
        *reinterpret_cast<v4f*>(Q + (r0 + 25 * rr) * 68 + 4 * cg) =
            (v4f){acc[0][rr] + bb[0], acc[1][rr] + bb[1],
                  acc[2][rr] + bb[2], acc[3][rr] + bb[3]};
}

// spin (relaxed sc0sc1, no cache maintenance), then pull partner half into LDS
__device__ __forceinline__ void kv_wait(const int* flagpt, int st,
    const float4* __restrict__ Gx, int b, int pbase,
    float4* __restrict__ KVs, int tid)
{
    if (tid == 0) {
        int f;
        for (;;) {
            asm volatile("global_load_dword %0, %1, off sc0 sc1\n\ts_waitcnt vmcnt(0)"
                         : "=v"(f) : "v"(flagpt) : "memory");
            if (f >= st) break;
            __builtin_amdgcn_s_sleep(8);
        }
    }
    __syncthreads();
    for (int i = tid; i < 1600; i += TPB) {
        int sl = i >> 5, h = i & 31;
        int sg = pbase + sl;
        const float4* gp = Gx + ((size_t)b * 100 + sg) * 32 + h;
        v4f v;
        asm volatile("global_load_dwordx4 %0, %1, off sc0 sc1\n\ts_waitcnt vmcnt(0)"
                     : "=v"(v) : "v"(gp) : "memory");
        *reinterpret_cast<v4f*>(KVs + h * 101 + sg) = v;
    }
    __syncthreads();
}

// attention: own 50 q-rows, full 100-key KV. task = (head, 4-query group)
__device__ __forceinline__ void attn_block(float* __restrict__ Q,
                                           const float4* __restrict__ KVs, int tid)
{
    if (tid < 416) {                           // 32 heads x 13 groups
        const int h = tid / 13;
        const int g = tid - 13 * h;
        const int lq0 = 4 * g;
        const float4* kv = KVs + h * 101;
        const float SCALE = 0.7071067811865476f * 1.4426950408889634f;  // /sqrt(2)*log2e
        float q0[4], q1[4];
#pragma unroll
        for (int j = 0; j < 4; ++j) {
            if (lq0 + j < RH) {
                float2 qv = *reinterpret_cast<const float2*>(Q + (lq0 + j) * 68 + 2 * h);
                q0[j] = qv.x * SCALE; q1[j] = qv.y * SCALE;
            } else { q0[j] = 0.f; q1[j] = 0.f; }
        }
        float mx[4] = {-1e30f, -1e30f, -1e30f, -1e30f};
#pragma unroll 4
        for (int s = 0; s < 100; ++s) {
            float4 k = kv[s];
#pragma unroll
            for (int j = 0; j < 4; ++j)
                mx[j] = fmaxf(mx[j], fmaf(q0[j], k.x, q1[j] * k.y));
        }
        float sum[4] = {0, 0, 0, 0}, a0[4] = {0, 0, 0, 0}, a1[4] = {0, 0, 0, 0};
#pragma unroll 4
        for (int s = 0; s < 100; ++s) {
            float4 k = kv[s];
#pragma unroll
            for (int j = 0; j < 4; ++j) {
                float e = EXP2(fmaf(q0[j], k.x, fmaf(q1[j], k.y, -mx[j])));
                sum[j] += e;
                a0[j] = fmaf(e, k.z, a0[j]);
                a1[j] = fmaf(e, k.w, a1[j]);
            }
        }
#pragma unroll
        for (int j = 0; j < 4; ++j) {
            if (lq0 + j < RH) {
                float inv = 1.f / sum[j];
                *reinterpret_cast<float2*>(Q + (lq0 + j) * 68 + 2 * h) =
                    make_float2(a0[j] * inv, a1[j] * inv);
            }
        }
    }
}

// out-projection + residual in place, 400 thr, 2 rows each
__device__ __forceinline__ void out_res(const float* __restrict__ Ain,
    const float* __restrict__ RW, const float* __restrict__ Bi,
    float* __restrict__ Sres, int tid)
{
    if (tid >= 400) return;
    const int r0 = tid >> 4, cg = tid & 15;
    v2f acc[4] = {};
    gemm_dual24<64, 132>(Ain + r0 * 68, Ain + (r0 + 25) * 68, RW + 4 * cg, acc);
    v4f bb = *reinterpret_cast<const v4f*>(Bi + 4 * cg);
#pragma unroll
    for (int rr = 0; rr < 2; ++rr) {
        float* sp = Sres + (r0 + 25 * rr) * 68 + 4 * cg;
        v4f s0 = *reinterpret_cast<v4f*>(sp);
        *reinterpret_cast<v4f*>(sp) =
            (v4f){acc[0][rr] + bb[0] + s0[0], acc[1][rr] + bb[1] + s0[1],
                  acc[2][rr] + bb[2] + s0[2], acc[3][rr] + bb[3] + s0[3]};
    }
}

// ---------------------------------------------------------------------------
__global__ __launch_bounds__(TPB) void k_fused(KParams prm, float* __restrict__ outp,
    float4* __restrict__ kvx0, float4* __restrict__ kvx1, int* __restrict__ flags)
{
    __shared__ float R0[RH * 68];        // s / mem
    __shared__ float R1[RH * 68];        // q / attn-out
    __shared__ float R3[RH * 68];        // t
    __shared__ float4 KVs[32 * 101];     // full-seq KV interleaved (k.xy, v.zw)
    __shared__ float RW[64 * 132];       // staged weights (K|V side-by-side)
    __shared__ float Hs[RH * 20];        // FFN hidden
    __shared__ float X1s[RH * 36];       // x1 pass0 -> pass1

    const int tid = threadIdx.x;
    const int b = blockIdx.x & 127;
    const int half = blockIdx.x >> 7;
    const int base = half * RH;
    const int pbase = RH - base;
    int* flagme = flags + (b * 2 + half) * 32;
    int* flagpt = flags + (b * 2 + 1 - half) * 32;

    const float* src = (const float*)prm.p[0];
    const float* tgt = (const float*)prm.p[1];

#define ATT_STAGE(Xq, Xkv, WQKV, BQ, WOUT, BO, SRES, st)                     \
    {                                                                        \
        float4* Gx = ((st) & 1) ? kvx1 : kvx0;                               \
        __syncthreads();              /* RW free, Xkv ready */               \
        ldwp<64, 64, 132>((WQKV) + 4096, RW, 0, tid);   /* K chunk */        \
        ldwp<64, 64, 132>((WQKV) + 8192, RW, 64, tid);  /* V chunk */        \
        __syncthreads();                                                     \
        kv_gemm(Xkv, RW, BQ, b, base, KVs, Gx, tid);                         \
        flag_pub(flagme, st, tid);    /* vmcnt + barrier + flag */           \
        ldwp<64, 64, 132>(WQKV, RW, 0, tid);            /* Q chunk */        \
        __syncthreads();                                                     \
        q_gemm(Xq, RW, BQ, R1, tid);                                         \
        kv_wait(flagpt, st, Gx, b, pbase, KVs, tid);                         \
        attn_block(R1, KVs, tid);                                            \
        __syncthreads();                                                     \
        ldwp<64, 64, 132>(WOUT, RW, 0, tid);                                 \
        __syncthreads();                                                     \
        out_res(R1, RW, BO, SRES, tid);                                      \
    }

#define FFN_STAGE(X, W1, B1, W2, B2)                                         \
    {                                                                        \
        __syncthreads();              /* X final, RW free */                 \
        ldwp<64, 16, 20>(W1, RW, 0, tid);                                    \
        __syncthreads();                                                     \
        if (tid < 200) {                                                     \
            const int r = tid >> 2, c4 = tid & 3;                            \
            float a[4] = {0, 0, 0, 0};                                       \
            gemm14v<64, 20>((X) + r * 68, RW + 4 * c4, a);                   \
            v4f bb = *reinterpret_cast<const v4f*>((B1) + 4 * c4);           \
            *reinterpret_cast<v4f*>(Hs + r * 20 + 4 * c4) =                  \
                (v4f){a[0] + bb[0], a[1] + bb[1], a[2] + bb[2], a[3] + bb[3]}; \
        }                                                                    \
        __syncthreads();                                                     \
        ldwp<16, 64, 68>(W2, RW, 0, tid);                                    \
        __syncthreads();                                                     \
        if (tid < 400) {                                                     \
            const int r0 = tid >> 4, cg = tid & 15;                          \
            v2f acc[4] = {};                                                 \
            gemm_dual24<16, 68>(Hs + r0 * 20, Hs + (r0 + 25) * 20,           \
                                RW + 4 * cg, acc);                           \
            v4f bb = *reinterpret_cast<const v4f*>((B2) + 4 * cg);           \
            _Pragma("unroll")                                                \
            for (int rr = 0; rr < 2; ++rr) {                                 \
                float* xp = (X) + (r0 + 25 * rr) * 68 + 4 * cg;              \
                v4f u = *reinterpret_cast<v4f*>(xp);                         \
                *reinterpret_cast<v4f*>(xp) =                                \
                    (v4f){acc[0][rr] + bb[0] + u[0], acc[1][rr] + bb[1] + u[1], \
                          acc[2][rr] + bb[2] + u[2], acc[3][rr] + bb[3] + u[3]}; \
            }                                                                \
        }                                                                    \
        __syncthreads();                                                     \
    }

    for (int pass = 0; pass < 2; ++pass) {
        const float* Wq_enc = (const float*)prm.p[2];
        const float* Beq    = (const float*)prm.p[3];
        const float* Wo_enc = (const float*)prm.p[4];
        const float* Beo    = (const float*)prm.p[5];
        const float* Wel1   = (const float*)prm.p[22];
        const float* Bel1   = (const float*)prm.p[23];
        const float* Wel2   = (const float*)prm.p[24];
        const float* Bel2   = (const float*)prm.p[25];
        const float* Wsa    = (const float*)prm.p[pass ? 14 : 6];
        const float* Bsa    = (const float*)prm.p[pass ? 15 : 7];
        const float* Wsao   = (const float*)prm.p[pass ? 16 : 8];
        const float* Bsao   = (const float*)prm.p[pass ? 17 : 9];
        const float* Wca    = (const float*)prm.p[pass ? 18 : 10];
        const float* Bca    = (const float*)prm.p[pass ? 19 : 11];
        const float* Wcao   = (const float*)prm.p[pass ? 20 : 12];
        const float* Bcao   = (const float*)prm.p[pass ? 21 : 13];
        const float* Wdl1   = (const float*)prm.p[pass ? 30 : 26];
        const float* Bdl1   = (const float*)prm.p[pass ? 31 : 27];
        const float* Wdl2   = (const float*)prm.p[pass ? 32 : 28];
        const float* Bdl2   = (const float*)prm.p[pass ? 33 : 29];
        const float* Wf     = (const float*)prm.p[34];
        const float* Bf     = (const float*)prm.p[35];
        float* outx = outp + (pass ? 409600 : 0);

        // ---- build s -> R0, tile tgt -> R3 ----
        __syncthreads();        // X1s (pass0 head) read; R0/R3/RW reuse
        for (int i = tid; i < RH * 64; i += TPB) {
            int l = i >> 6, d = i & 63;
            int lg = base + l;
            float sv = src[((size_t)lg * 128 + b) * 32 + (d & 31)];
            float v;
            if (d < 32) v = sv;
            else if (pass == 0) v = 0.f;
            else { float df = X1s[l * 36 + (d - 32)] - sv; v = df * df; }
            float div = __expf((float)d * -0.14391156831212787f);
            float pe = 1.4142135623730951f * __sinf((float)lg * div + 0.7853981633974483f);
            R0[l * 68 + d] = v * SQ32 + pe;
        }
        for (int i = tid; i < RH * 8; i += TPB) {
            int l = i >> 3, q4 = i & 7;
            int lg = base + l;
            float4 tv = *reinterpret_cast<const float4*>(tgt + ((size_t)lg * 128 + b) * 32 + 4 * q4);
            *reinterpret_cast<float4*>(R3 + l * 68 + 4 * q4) = tv;
            *reinterpret_cast<float4*>(R3 + l * 68 + 32 + 4 * q4) = tv;
        }

        // ---- encoder self-attention + FFN (R0 becomes mem) ----
        ATT_STAGE(R0, R0, Wq_enc, Beq, Wo_enc, Beo, R0, pass * 3 + 1)
        FFN_STAGE(R0, Wel1, Bel1, Wel2, Bel2)

        // ---- decoder self-attention ----
        ATT_STAGE(R3, R3, Wsa, Bsa, Wsao, Bsao, R3, pass * 3 + 2)

        // ---- decoder cross-attention (q from t, kv from mem) ----
        ATT_STAGE(R3, R0, Wca, Bca, Wcao, Bcao, R3, pass * 3 + 3)
        FFN_STAGE(R3, Wdl1, Bdl1, Wdl2, Bdl2)

        // ---- head: sigmoid(R3 @ Wf^T + bf) -> out (+ X1s for pass1's c) ----
        ldwp<64, 32, 36>(Wf, RW, 0, tid);    // FFN_STAGE ended with barrier
        __syncthreads();
        if (tid < 400) {
            const int r = tid >> 3, lp = tid & 7;
            float a[4] = {0, 0, 0, 0};
            gemm14v<64, 36>(R3 + r * 68, RW + 4 * lp, a);
            v4f bb = *reinterpret_cast<const v4f*>(Bf + 4 * lp);
            v4f o;
#pragma unroll
            for (int c = 0; c < 4; ++c) o[c] = 1.f / (1.f + __expf(-(a[c] + bb[c])));
            int rg = base + r;
            *reinterpret_cast<v4f*>(outx + ((size_t)rg * 128 + b) * 32 + 4 * lp) = o;
            if (pass == 0)
                *reinterpret_cast<v4f*>(X1s + r * 36 + 4 * lp) = o;
        }
    }
#undef ATT_STAGE
#undef FFN_STAGE
}

// ---------------------------------------------------------------------------
extern "C" void kernel_launch(void* const* d_in, const int* in_sizes, int n_in,
                              void* d_out, int out_size, void* d_ws, size_t ws_size,
                              hipStream_t stream)
{
    KParams prm;
    for (int i = 0; i < 36; ++i) prm.p[i] = d_in[i];
    float4* kvx0 = (float4*)d_ws;                 // 409600 float4 = 6.55 MB
    float4* kvx1 = kvx0 + 409600;                 // parity double-buffer
    int* flags = (int*)(kvx1 + 409600);           // 256 flags, 128B apart
    k_fused<<<dim3(256), dim3(TPB), 0, stream>>>(prm, (float*)d_out, kvx0, kvx1, flags);
}